// Round 9
// baseline (319.809 us; speedup 1.0000x reference)
//
#include <hip/hip_runtime.h>

// LIF neuron scan: 16384 neurons x 2048 sequential steps.
//
// R10 (producer/consumer wave specialization, S=8) = best: kernel ~69 us,
// ~5.8 TB/s effective delivery (402 MB total traffic; floor ~64 us @6.3).
// R11 (S=16, half the barriers) was neutral->slightly worse: barriers are
// not the residual; per-CU delivery pace is. Revert to S=8.
//
// R12 experiment: producer loads TEMPORAL instead of nontemporal. Counters
// show FETCH_SIZE = 134 MB = exactly half the 268 MB input every round: the
// 256 MB L3 serves ~50% of fetches across repeated dispatches DESPITE the
// NT hint requesting minimal retention. If NT degrades L3 retention of the
// near-resident input streams, temporal loads raise the hit rate and cut
// HBM fetch. NT stores stay (write-once output must not evict input in L3).
//
// Roles (256-thread block, 64 neurons/block, 256 blocks = 256 CUs):
//   w0: I-producer  (dwordx4 -> 4 reg sets -> ds_write_b128, distance-3)
//   w1: Z-producer  (same, Z stream)
//   w2: spike storer (ds_read_b128 -> NT dwordx4 stores, lagged 1 section)
//   w3: consumer    (pure scan: ds_read_b32 + VALU chain + spike ds_write)
// Sections of S=8 chunks (32 timesteps), 64 sections; sync via raw
// s_barrier + lgkmcnt(0) ONLY (no vmcnt drain -- producer loads and storer
// stores stay in flight across sections).
//
// Exactness (binary spike output): contract(off), reference op order:
//   V = (V + 0.05f*(I-V)) + nz ; s = V>=Vth ; V = s?0:V ;
//   Vth = s ? min(max(Vth+0.1f,0.5f),2.0f) : Vth

constexpr int N  = 16384;   // neurons
constexpr int T  = 2048;    // sequential steps
constexpr int U  = 4;       // timesteps per chunk
constexpr int CH = T / U;   // 512 chunks
constexpr int S  = 8;       // chunks per section
constexpr int NSEC = CH / S;// 64 sections

static_assert(NSEC % 4 == 0, "j-unroll of 4 needs NSEC % 4 == 0");

typedef float f4v __attribute__((ext_vector_type(4)));

// Raw barrier: drain LDS ops (visibility to other waves), do NOT drain
// vmcnt (keeps producer loads / storer stores in flight across sections).
#define BAR() do {                                                            \
    asm volatile("s_waitcnt lgkmcnt(0)" ::: "memory");                        \
    __builtin_amdgcn_s_barrier();                                             \
    __builtin_amdgcn_sched_barrier(0);                                        \
} while (0)

__global__
__attribute__((amdgpu_flat_work_group_size(256, 256)))
void TorchLIFNeuronGroup_85152021610615_kernel(const float* __restrict__ I,
                                               const float* __restrict__ Z,
                                               float* __restrict__ O) {
    #pragma clang fp contract(off)
    // IZ[parity][stream][chunk][row][col] ; SB[parity][chunk][row][col]
    __shared__ __align__(16) float IZ[2][2][S][U][64];
    __shared__ __align__(16) float SB[2][S][U][64];

    const int w    = threadIdx.x >> 6;   // wave role
    const int lane = threadIdx.x & 63;
    const int g    = lane >> 4;          // row within chunk (0..3)
    const int c4   = (lane & 15) << 2;   // col group (0,4,..,60)
    const size_t laneOff = (size_t)g * N + c4;
    const size_t nbase   = (size_t)blockIdx.x * 64;

    const float* pfx  = (w == 0 ? I : Z) + nbase + laneOff;  // producers
    float*       opfx = O + nbase + laneOff;                 // storer

    float V   = 0.0f;   // consumer state
    float Vth = 1.0f;
    f4v rg[4][S];       // producer register sets (section s -> set s&3)
    f4v sv[S];          // storer staging regs

    // ---- Prologue: producers load sections 0..2, ds_write section 0. ----
    if (w <= 1) {
        #pragma unroll
        for (int s = 0; s < 3; ++s)
            #pragma unroll
            for (int c = 0; c < S; ++c)
                rg[s][c] = *reinterpret_cast<const f4v*>(
                    pfx + (size_t)(U * (S * s + c)) * N);
        #pragma unroll
        for (int c = 0; c < S; ++c)
            *reinterpret_cast<f4v*>(&IZ[0][w][c][0][0] + lane * 4) = rg[0][c];
    }
    BAR();

    // ---- Main: 64 sections, j-unrolled by 4 so all &3/&1 are static. ----
    #pragma clang loop unroll(disable)
    for (int kb = 0; kb < NSEC / 4; ++kb) {
        #pragma unroll
        for (int j = 0; j < 4; ++j) {
            const int k = kb * 4 + j;    // section being computed
            if (w <= 1) {
                // ds_write section k+1 (regs loaded at iter k-2; the
                // compiler emits a precise vmcnt wait on rg[(j+1)&3]).
                if (k <= NSEC - 2) {
                    #pragma unroll
                    for (int c = 0; c < S; ++c)
                        *reinterpret_cast<f4v*>(
                            &IZ[(j + 1) & 1][w][c][0][0] + lane * 4) =
                            rg[(j + 1) & 3][c];
                }
                // issue temporal loads for section k+3 into set (j+3)&3.
                if (k <= NSEC - 4) {
                    #pragma unroll
                    for (int c = 0; c < S; ++c)
                        rg[(j + 3) & 3][c] = *reinterpret_cast<const f4v*>(
                            pfx + (size_t)(U * (S * (k + 3) + c)) * N);
                }
            } else if (w == 2) {
                // store section k-1 spikes (written by consumer at iter k-1).
                if (k >= 1) {
                    #pragma unroll
                    for (int c = 0; c < S; ++c)
                        sv[c] = *reinterpret_cast<const f4v*>(
                            &SB[(j + 1) & 1][c][0][0] + lane * 4);
                    #pragma unroll
                    for (int c = 0; c < S; ++c)
                        __builtin_nontemporal_store(sv[c],
                            reinterpret_cast<f4v*>(
                                opfx + (size_t)(U * (S * (k - 1) + c)) * N));
                }
            } else {
                // consumer: scan section k from IZ[j&1], 1-chunk read-ahead.
                float ci[2][U], cz[2][U];
                #pragma unroll
                for (int u = 0; u < U; ++u) {
                    ci[0][u] = IZ[j & 1][0][0][u][lane];
                    cz[0][u] = IZ[j & 1][1][0][u][lane];
                }
                #pragma unroll
                for (int c = 0; c < S; ++c) {
                    if (c + 1 < S) {
                        #pragma unroll
                        for (int u = 0; u < U; ++u) {
                            ci[(c + 1) & 1][u] = IZ[j & 1][0][c + 1][u][lane];
                            cz[(c + 1) & 1][u] = IZ[j & 1][1][c + 1][u][lane];
                        }
                    }
                    #pragma unroll
                    for (int u = 0; u < U; ++u) {
                        float Iv = ci[c & 1][u];
                        float Zv = cz[c & 1][u];
                        float dd = Iv - V;
                        float v1 = V + 0.05f * dd;          // DT/TAU
                        float v2 = v1 + Zv;
                        bool  s  = (v2 >= Vth);
                        V = s ? 0.0f : v2;
                        float nth = fminf(fmaxf(Vth + 0.1f, 0.5f), 2.0f);
                        Vth = s ? nth : Vth;
                        SB[j & 1][c][u][lane] = s ? 1.0f : 0.0f;
                    }
                }
            }
            BAR();
        }
    }

    // ---- Epilogue: store the last section's spikes (parity 63&1 = 1). ----
    if (w == 2) {
        #pragma unroll
        for (int c = 0; c < S; ++c)
            sv[c] = *reinterpret_cast<const f4v*>(
                &SB[1][c][0][0] + lane * 4);
        #pragma unroll
        for (int c = 0; c < S; ++c)
            __builtin_nontemporal_store(sv[c],
                reinterpret_cast<f4v*>(
                    opfx + (size_t)(U * (S * (NSEC - 1) + c)) * N));
    }
}

extern "C" void kernel_launch(void* const* d_in, const int* in_sizes, int n_in,
                              void* d_out, int out_size, void* d_ws, size_t ws_size,
                              hipStream_t stream) {
    const float* input_current = (const float*)d_in[0];
    const float* noise         = (const float*)d_in[1];
    float* out                 = (float*)d_out;

    TorchLIFNeuronGroup_85152021610615_kernel<<<N / 64, 256, 0, stream>>>(
        input_current, noise, out);
}

// Round 10
// 289.401 us; speedup vs baseline: 1.1051x; 1.1051x over previous
//
#include <hip/hip_runtime.h>

// LIF neuron scan: 16384 neurons x 2048 sequential steps.
//
// R10: producer/consumer wave specialization. R3/R9 both converge to
// ~180 ns/stage because ONE wave serially issues loads, waits vmcnt,
// stages LDS, computes, and retires NT stores with 1 wave/SIMD and no
// TLP. Split roles over 4 waves (256-thread block, 64 neurons/block,
// 256 blocks = 256 CUs):
//   w0: I-producer  (NT dwordx4 -> 4 reg sets -> ds_write_b128)
//   w1: Z-producer  (same, Z stream)
//   w2: spike storer (ds_read_b128 ring -> NT dwordx4 stores)
//   w3: consumer    (pure scan: ds_read_b32 + VALU chain + spike writes)
// Sections of S=8 chunks (32 timesteps); 64 sections; per-section sync via
// raw s_barrier + lgkmcnt(0) ONLY -- __syncthreads() would drain vmcnt(0)
// and destroy the producers' in-flight pipeline (the GEMM barrier-drain
// stall). Producers load section k+3 at iter k, ds_write section k+1 from
// regs loaded at iter k-2 (vmcnt wait is a precise register dep: ~1.3 us
// latency cover; 2 waves x ~24 KB in flight per CU = ~10 MB chip-wide).
// LDS ring: 2 sections x {I,Z} (32 KB) + 2-section spike buffer (16 KB).
// Consumer reads stride-256B b32 (2 lanes/bank = free); storer reads the
// spike chunk linearly (b128) and stores with the row/col lane mapping.
//
// Post-mortems locked in:
//  R11 (S=16, half the barriers): neutral -> barriers are not the residual.
//  R12 (temporal producer loads): 131 us, VGPR 132->88 -> the NT-load
//      codegen is load-bearing for the distance-3 pipeline (plain loads
//      collapse the in-flight ring); FETCH unchanged -> L3 insensitive.
//  => This R10 form is the measured optimum: ~69 us vs ~64 us floor
//     (402 MB total traffic @ 6.3 TB/s achievable).
//
// Exactness (binary spike output): contract(off), reference op order:
//   V = (V + 0.05f*(I-V)) + nz ; s = V>=Vth ; V = s?0:V ;
//   Vth = s ? min(max(Vth+0.1f,0.5f),2.0f) : Vth

constexpr int N  = 16384;   // neurons
constexpr int T  = 2048;    // sequential steps
constexpr int U  = 4;       // timesteps per chunk
constexpr int CH = T / U;   // 512 chunks
constexpr int S  = 8;       // chunks per section
constexpr int NSEC = CH / S;// 64 sections

static_assert(NSEC % 4 == 0, "j-unroll of 4 needs NSEC % 4 == 0");

typedef float f4v __attribute__((ext_vector_type(4)));

// Raw barrier: drain LDS ops (visibility to other waves), do NOT drain
// vmcnt (keeps producer loads / storer stores in flight across sections).
#define BAR() do {                                                            \
    asm volatile("s_waitcnt lgkmcnt(0)" ::: "memory");                        \
    __builtin_amdgcn_s_barrier();                                             \
    __builtin_amdgcn_sched_barrier(0);                                        \
} while (0)

__global__
__attribute__((amdgpu_flat_work_group_size(256, 256)))
void TorchLIFNeuronGroup_85152021610615_kernel(const float* __restrict__ I,
                                               const float* __restrict__ Z,
                                               float* __restrict__ O) {
    #pragma clang fp contract(off)
    // IZ[parity][stream][chunk][row][col] ; SB[parity][chunk][row][col]
    __shared__ __align__(16) float IZ[2][2][S][U][64];
    __shared__ __align__(16) float SB[2][S][U][64];

    const int w    = threadIdx.x >> 6;   // wave role
    const int lane = threadIdx.x & 63;
    const int g    = lane >> 4;          // row within chunk (0..3)
    const int c4   = (lane & 15) << 2;   // col group (0,4,..,60)
    const size_t laneOff = (size_t)g * N + c4;
    const size_t nbase   = (size_t)blockIdx.x * 64;

    const float* pfx  = (w == 0 ? I : Z) + nbase + laneOff;  // producers
    float*       opfx = O + nbase + laneOff;                 // storer

    float V   = 0.0f;   // consumer state
    float Vth = 1.0f;
    f4v rg[4][S];       // producer register sets (section s -> set s&3)
    f4v sv[S];          // storer staging regs

    // ---- Prologue: producers load sections 0..2, ds_write section 0. ----
    if (w <= 1) {
        #pragma unroll
        for (int s = 0; s < 3; ++s)
            #pragma unroll
            for (int c = 0; c < S; ++c)
                rg[s][c] = __builtin_nontemporal_load(
                    reinterpret_cast<const f4v*>(
                        pfx + (size_t)(U * (S * s + c)) * N));
        #pragma unroll
        for (int c = 0; c < S; ++c)
            *reinterpret_cast<f4v*>(&IZ[0][w][c][0][0] + lane * 4) = rg[0][c];
    }
    BAR();

    // ---- Main: 64 sections, j-unrolled by 4 so all &3/&1 are static. ----
    #pragma clang loop unroll(disable)
    for (int kb = 0; kb < NSEC / 4; ++kb) {
        #pragma unroll
        for (int j = 0; j < 4; ++j) {
            const int k = kb * 4 + j;    // section being computed
            if (w <= 1) {
                // ds_write section k+1 (regs loaded at iter k-2; the
                // compiler emits a precise vmcnt wait on rg[(j+1)&3]).
                if (k <= NSEC - 2) {
                    #pragma unroll
                    for (int c = 0; c < S; ++c)
                        *reinterpret_cast<f4v*>(
                            &IZ[(j + 1) & 1][w][c][0][0] + lane * 4) =
                            rg[(j + 1) & 3][c];
                }
                // issue NT loads for section k+3 into set (j+3)&3.
                if (k <= NSEC - 4) {
                    #pragma unroll
                    for (int c = 0; c < S; ++c)
                        rg[(j + 3) & 3][c] = __builtin_nontemporal_load(
                            reinterpret_cast<const f4v*>(
                                pfx + (size_t)(U * (S * (k + 3) + c)) * N));
                }
            } else if (w == 2) {
                // store section k-1 spikes (written by consumer at iter k-1).
                if (k >= 1) {
                    #pragma unroll
                    for (int c = 0; c < S; ++c)
                        sv[c] = *reinterpret_cast<const f4v*>(
                            &SB[(j + 1) & 1][c][0][0] + lane * 4);
                    #pragma unroll
                    for (int c = 0; c < S; ++c)
                        __builtin_nontemporal_store(sv[c],
                            reinterpret_cast<f4v*>(
                                opfx + (size_t)(U * (S * (k - 1) + c)) * N));
                }
            } else {
                // consumer: scan section k from IZ[j&1], 1-chunk read-ahead.
                float ci[2][U], cz[2][U];
                #pragma unroll
                for (int u = 0; u < U; ++u) {
                    ci[0][u] = IZ[j & 1][0][0][u][lane];
                    cz[0][u] = IZ[j & 1][1][0][u][lane];
                }
                #pragma unroll
                for (int c = 0; c < S; ++c) {
                    if (c + 1 < S) {
                        #pragma unroll
                        for (int u = 0; u < U; ++u) {
                            ci[(c + 1) & 1][u] = IZ[j & 1][0][c + 1][u][lane];
                            cz[(c + 1) & 1][u] = IZ[j & 1][1][c + 1][u][lane];
                        }
                    }
                    #pragma unroll
                    for (int u = 0; u < U; ++u) {
                        float Iv = ci[c & 1][u];
                        float Zv = cz[c & 1][u];
                        float dd = Iv - V;
                        float v1 = V + 0.05f * dd;          // DT/TAU
                        float v2 = v1 + Zv;
                        bool  s  = (v2 >= Vth);
                        V = s ? 0.0f : v2;
                        float nth = fminf(fmaxf(Vth + 0.1f, 0.5f), 2.0f);
                        Vth = s ? nth : Vth;
                        SB[j & 1][c][u][lane] = s ? 1.0f : 0.0f;
                    }
                }
            }
            BAR();
        }
    }

    // ---- Epilogue: store the last section's spikes (parity 63&1 = 1). ----
    if (w == 2) {
        #pragma unroll
        for (int c = 0; c < S; ++c)
            sv[c] = *reinterpret_cast<const f4v*>(
                &SB[1][c][0][0] + lane * 4);
        #pragma unroll
        for (int c = 0; c < S; ++c)
            __builtin_nontemporal_store(sv[c],
                reinterpret_cast<f4v*>(
                    opfx + (size_t)(U * (S * (NSEC - 1) + c)) * N));
    }
}

extern "C" void kernel_launch(void* const* d_in, const int* in_sizes, int n_in,
                              void* d_out, int out_size, void* d_ws, size_t ws_size,
                              hipStream_t stream) {
    const float* input_current = (const float*)d_in[0];
    const float* noise         = (const float*)d_in[1];
    float* out                 = (float*)d_out;

    TorchLIFNeuronGroup_85152021610615_kernel<<<N / 64, 256, 0, stream>>>(
        input_current, noise, out);
}